// Round 5
// baseline (3019.813 us; speedup 1.0000x reference)
//
#include <hip/hip_runtime.h>
#include <cstdint>
#include <cstddef>

#define N_TOK 65536
#define DIM 512
#define FF 2048
#define NE 8

typedef __attribute__((ext_vector_type(8))) short short8;
typedef __attribute__((ext_vector_type(4))) float f32x4;

__device__ __forceinline__ unsigned f2bf(float f) {
  unsigned u = __builtin_bit_cast(unsigned, f);
  u = u + 0x7fffu + ((u >> 16) & 1u);
  return (u >> 16) & 0xffffu;
}

__device__ __forceinline__ void gload_lds16(const void* g, void* l) {
  __builtin_amdgcn_global_load_lds((const __attribute__((address_space(1))) void*)g,
                                   (__attribute__((address_space(3))) void*)l, 16, 0, 0);
}

// ---------------- transpose + cast: in (rows x cols) f32 -> out (cols x rows) bf16, per expert
__global__ __launch_bounds__(256) void k_transpose_cast(
    const float* __restrict__ in, unsigned short* __restrict__ outp, int rows, int cols)
{
  __shared__ float tile[32][33];
  const float* ine = in + (size_t)blockIdx.z * rows * cols;
  unsigned short* oute = outp + (size_t)blockIdx.z * rows * cols;
  int tx = threadIdx.x & 31, ty = threadIdx.x >> 5;
  int r0 = blockIdx.y * 32, c0 = blockIdx.x * 32;
#pragma unroll
  for (int i = 0; i < 4; ++i)
    tile[ty + i*8][tx] = ine[(size_t)(r0 + ty + i*8)*cols + c0 + tx];
  __syncthreads();
#pragma unroll
  for (int i = 0; i < 4; ++i) {
    int r = c0 + ty + i*8, c = r0 + tx;
    oute[(size_t)r*rows + c] = (unsigned short)f2bf(tile[tx][ty + i*8]);
  }
}

// ---------------- router pass 1: logits, top-2, weight; per-expert counts only
__global__ __launch_bounds__(256) void k_router(
    const float* __restrict__ x, const float* __restrict__ Wr,
    int2* __restrict__ tinfo, int* __restrict__ cnt)
{
  __shared__ int lcnt[8];
  int tid = threadIdx.x, lane = tid & 63, wv = tid >> 6;
  if (tid < 8) lcnt[tid] = 0;
  float wr[8][8];
#pragma unroll
  for (int j = 0; j < 8; ++j) {
    const float4* p = (const float4*)(Wr + (size_t)(lane*8 + j)*NE);
    float4 a = p[0], b = p[1];
    wr[j][0]=a.x; wr[j][1]=a.y; wr[j][2]=a.z; wr[j][3]=a.w;
    wr[j][4]=b.x; wr[j][5]=b.y; wr[j][6]=b.z; wr[j][7]=b.w;
  }
  __syncthreads();
  int t0 = blockIdx.x*64 + wv*16;
  for (int it = 0; it < 16; ++it) {
    int t = t0 + it;
    const float4* xp = (const float4*)(x + (size_t)t*DIM + lane*8);
    float4 v0 = xp[0], v1 = xp[1];
    float xv[8] = {v0.x,v0.y,v0.z,v0.w,v1.x,v1.y,v1.z,v1.w};
    float lg[8];
#pragma unroll
    for (int e2 = 0; e2 < 8; ++e2) lg[e2] = 0.f;
#pragma unroll
    for (int j = 0; j < 8; ++j)
#pragma unroll
      for (int e2 = 0; e2 < 8; ++e2) lg[e2] += xv[j]*wr[j][e2];
#pragma unroll
    for (int off = 32; off >= 1; off >>= 1)
#pragma unroll
      for (int e2 = 0; e2 < 8; ++e2) lg[e2] += __shfl_xor(lg[e2], off, 64);
    int e0 = 0; float v0m = lg[0];
#pragma unroll
    for (int e2 = 1; e2 < 8; ++e2) if (lg[e2] > v0m) { v0m = lg[e2]; e0 = e2; }
    int e1 = -1; float v1m = -3.0e38f;
#pragma unroll
    for (int e2 = 0; e2 < 8; ++e2) if (e2 != e0 && lg[e2] > v1m) { v1m = lg[e2]; e1 = e2; }
    float w0 = 1.f / (1.f + __expf((v1m - v0m) * 0.4f));   // 1/T = 1/2.5
    if (lane == 0) {
      atomicAdd(&lcnt[e0], 1);
      atomicAdd(&lcnt[e1], 1);
      tinfo[t] = make_int2(e0 | (e1 << 8), __float_as_int(w0));
    }
  }
  __syncthreads();
  if (tid < 8) atomicAdd(&cnt[tid*16], lcnt[tid]);
}

// ---------------- pass 2: exclusive scan of counts -> bases; zero cursors
__global__ void k_offsets(int* cnt) {
  if (threadIdx.x == 0) {
    int base = 0;
    for (int e2 = 0; e2 < 8; ++e2) {
      cnt[e2*16 + 1] = base;
      base += cnt[e2*16];
      cnt[e2*16 + 2] = 0;
    }
  }
}

// ---------------- pass 3: gather x rows (bf16) into contiguous per-expert regions
__global__ __launch_bounds__(256) void k_fill(
    const float* __restrict__ x, const int2* __restrict__ tinfo,
    unsigned short* __restrict__ xg, int* __restrict__ tokl,
    float* __restrict__ pwl, int* __restrict__ cnt)
{
  __shared__ int lc[8], lbase[8], gb[8];
  __shared__ unsigned char ce[128];
  __shared__ int csl[128];
  __shared__ float cw[128];
  int tid = threadIdx.x;
  if (tid < 8) { lc[tid] = 0; gb[tid] = cnt[tid*16 + 1]; }
  __syncthreads();
  if (tid < 64) {
    int t = blockIdx.x*64 + tid;
    int2 inf = tinfo[t];
    int e0 = inf.x & 0xff, e1 = (inf.x >> 8) & 0xff;
    float w0 = __int_as_float(inf.y);
    int i0 = tid*2, i1 = i0 + 1;
    ce[i0] = (unsigned char)e0; cw[i0] = w0;        csl[i0] = atomicAdd(&lc[e0], 1);
    ce[i1] = (unsigned char)e1; cw[i1] = 1.f - w0;  csl[i1] = atomicAdd(&lc[e1], 1);
  }
  __syncthreads();
  if (tid < 8) lbase[tid] = atomicAdd(&cnt[tid*16 + 2], lc[tid]);
  __syncthreads();
  int lane = tid & 63, wv = tid >> 6;
#pragma unroll
  for (int j = 0; j < 32; ++j) {
    int i = wv*32 + j;
    int t = blockIdx.x*64 + (i >> 1);
    int e2 = ce[i];
    int gpos = gb[e2] + lbase[e2] + csl[i];
    const float4* src = (const float4*)(x + (size_t)t*DIM + lane*8);
    float4 v0 = src[0], v1 = src[1];
    uint4 pk;
    pk.x = f2bf(v0.x) | (f2bf(v0.y) << 16);
    pk.y = f2bf(v0.z) | (f2bf(v0.w) << 16);
    pk.z = f2bf(v1.x) | (f2bf(v1.y) << 16);
    pk.w = f2bf(v1.z) | (f2bf(v1.w) << 16);
    *(uint4*)(xg + (size_t)gpos*DIM + lane*8) = pk;
    if (lane == 0) { tokl[gpos] = t; pwl[gpos] = cw[i]; }
  }
}

// ---------------- fused expert FFN v5: m97-mode.
// 64 tok/block, 256 thr (4 waves), 16x16x32 MFMA, 64 KB LDS -> 2 blocks/CU (TLP hides drains).
// G1: wave = 64t x 32f. A from global xg (reg dbuf), B (W1^T chunk [128f][64k]) LDS, reused x4 row-groups.
// G2: wave = 64t x 128d. A (h) LDS [64][128f] granule^row, B (W2^T chunk [256d][32k]) LDS.
// Simple schedule: stage(next); MFMA(cur); __syncthreads(). No vmcnt ledger.
// h overlays w1-buf0 (last buf0 read at kk=6; restaged only at next fi pre-phase).
__global__ __launch_bounds__(256, 2) void k_ffn(
    const unsigned short* __restrict__ xg,
    const unsigned short* __restrict__ w1t,   // (E, F, D) bf16
    const unsigned short* __restrict__ w2t,   // (E, D, F) bf16
    const float* __restrict__ b1, const float* __restrict__ b2,
    const int* __restrict__ tokl, const float* __restrict__ pwl,
    const int* __restrict__ cnt, float* __restrict__ out)
{
  const int e = blockIdx.x & 7;            // expert <-> XCD affinity
  const int tile = blockIdx.x >> 3;
  const int count = cnt[e*16];
  const int row0 = tile * 64;
  if (row0 >= count) return;
  const int gbase = cnt[e*16 + 1];

  __shared__ __align__(16) unsigned short lds[32768];   // 64 KB total
  unsigned short* w1p[2] = { lds, lds + 8192 };          // [128f][64k] each, 16 KB
  unsigned short* w2p[2] = { lds + 16384, lds + 24576 }; // [256d][32k] each, 16 KB
  unsigned short* hsm = lds;                             // overlay on w1p[0]: [64t][128f]

  const int tid = threadIdx.x, lane = tid & 63, wv = tid >> 6;
  const int r16 = lane & 15, g4 = lane >> 4;

  const unsigned short* w1e = w1t + (size_t)e*FF*DIM;
  const unsigned short* w2e = w2t + (size_t)e*DIM*FF;
  const unsigned short* xge = xg + (size_t)(gbase + row0)*DIM;

  int rmax = count - row0 - 1; if (rmax > 63) rmax = 63;
  const unsigned short* xrow[4];
#pragma unroll
  for (int rg = 0; rg < 4; ++rg) {
    int rr = rg*16 + r16; if (rr > rmax) rr = rmax;
    xrow[rg] = xge + (size_t)rr*DIM;
  }

  const int sr8 = tid >> 3, sg8 = tid & 7;   // w1 staging coords
  const int sr4 = tid >> 2, sg4 = tid & 3;   // w2 staging coords

  auto stage_w1 = [&](unsigned short* buf, int f0_, int kk_) {
#pragma unroll
    for (int j = 0; j < 4; ++j) {
      int f = j*32 + sr8;
      gload_lds16(w1e + (size_t)(f0_ + f)*DIM + kk_*64 + ((sg8 ^ (f & 7))*8),
                  buf + j*2048 + tid*8);
    }
  };
  auto stage_w2 = [&](unsigned short* buf, int f0_, int dh_, int ss_) {
#pragma unroll
    for (int j = 0; j < 4; ++j) {
      int dc = j*64 + sr4;
      gload_lds16(w2e + (size_t)(dh_*256 + dc)*FF + f0_ + ss_*32 + ((sg4 ^ ((dc >> 2) & 3))*8),
                  buf + j*2048 + tid*8);
    }
  };

  const f32x4 fz = {0.f, 0.f, 0.f, 0.f};
  f32x4 acc[4][2][4];                         // [rg][dh][n]
#pragma unroll
  for (int rg = 0; rg < 4; ++rg)
#pragma unroll
    for (int dh = 0; dh < 2; ++dh)
#pragma unroll
      for (int n = 0; n < 4; ++n) acc[rg][dh][n] = fz;

  short8 xa[2][4][2];                         // [buf][rg][k2]
#define XLOAD(B, KK) do { _Pragma("unroll") \
  for (int rg_ = 0; rg_ < 4; ++rg_) { _Pragma("unroll") \
    for (int k2_ = 0; k2_ < 2; ++k2_) \
      xa[B][rg_][k2_] = *(const short8*)(xrow[rg_] + (KK)*64 + k2_*32 + g4*8); } } while (0)

  for (int fi = 0; fi < 16; ++fi) {
    const int f0 = fi << 7;

    // ---- pre-phase: w1 chunk0 -> buf0 (hsm region free: all G2 reads done), x(0), b1 ----
    stage_w1(w1p[0], f0, 0);
    XLOAD(0, 0);
    float b1v[2];
    b1v[0] = b1[e*FF + f0 + wv*32 + r16];
    b1v[1] = b1[e*FF + f0 + wv*32 + 16 + r16];
    __syncthreads();

    f32x4 hacc[4][2];
#pragma unroll
    for (int rg = 0; rg < 4; ++rg) { hacc[rg][0] = fz; hacc[rg][1] = fz; }

    // ---------- GEMM1: 8 K64-phases ----------
#pragma unroll
    for (int kk = 0; kk < 8; ++kk) {
      unsigned short* bcur = w1p[kk & 1];
      if (kk < 7) { XLOAD((kk + 1) & 1, kk + 1); stage_w1(w1p[(kk + 1) & 1], f0, kk + 1); }
      if (kk == 6) stage_w2(w2p[0], f0, 0, 0);
      short8 bf[2][2];
#pragma unroll
      for (int n = 0; n < 2; ++n)
#pragma unroll
        for (int k2 = 0; k2 < 2; ++k2) {
          int fl = wv*32 + n*16 + r16;
          bf[n][k2] = *(const short8*)(bcur + fl*64 + (((k2*4 + g4) ^ (fl & 7))*8));
        }
      __builtin_amdgcn_s_setprio(1);
#pragma unroll
      for (int rg = 0; rg < 4; ++rg)
#pragma unroll
        for (int k2 = 0; k2 < 2; ++k2)
#pragma unroll
          for (int n = 0; n < 2; ++n)
            hacc[rg][n] = __builtin_amdgcn_mfma_f32_16x16x32_bf16(
                xa[kk & 1][rg][k2], bf[n][k2], hacc[rg][n], 0, 0, 0);
      __builtin_amdgcn_s_setprio(0);
      __syncthreads();
    }

    // ---------- bias + gelu -> hsm [64t][128f], granule ^ row (overlay on w1p[0]) ----------
#pragma unroll
    for (int n = 0; n < 2; ++n) {
      int f = wv*32 + n*16 + r16;
      int g = f >> 3;
      float bias = b1v[n];
#pragma unroll
      for (int rg = 0; rg < 4; ++rg)
#pragma unroll
        for (int i = 0; i < 4; ++i) {
          int row = rg*16 + g4*4 + i;
          float v = hacc[rg][n][i] + bias;
          float u = 0.7978845608028654f * (v + 0.044715f*v*v*v);
          float gl = v / (1.f + __expf(-2.f*u));      // tanh-approx gelu
          hsm[row*128 + ((g ^ (row & 15))*8) + (f & 7)] = (unsigned short)f2bf(gl);
        }
    }
    __syncthreads();   // h visible to all waves

    // ---------- GEMM2: 8 K32-phases (dh 0..1 x ss 0..3) ----------
#pragma unroll
    for (int c = 0; c < 8; ++c) {
      int dh = c >> 2, ss = c & 3;
      unsigned short* bcur = w2p[c & 1];
      if (c < 7) { int cn = c + 1; stage_w2(w2p[cn & 1], f0, cn >> 2, cn & 3); }
      short8 av[4];
#pragma unroll
      for (int rg = 0; rg < 4; ++rg) {
        int row = rg*16 + r16;
        av[rg] = *(const short8*)(hsm + row*128 + (((ss*4 + g4) ^ r16)*8));
      }
      short8 bv[4];
#pragma unroll
      for (int n = 0; n < 4; ++n) {
        int dc = wv*64 + n*16 + r16;
        bv[n] = *(const short8*)(bcur + dc*32 + ((g4 ^ ((dc >> 2) & 3))*8));
      }
      __builtin_amdgcn_s_setprio(1);
#pragma unroll
      for (int rg = 0; rg < 4; ++rg)
#pragma unroll
        for (int n = 0; n < 4; ++n)
          acc[rg][dh][n] = __builtin_amdgcn_mfma_f32_16x16x32_bf16(
              av[rg], bv[n], acc[rg][dh][n], 0, 0, 0);
      __builtin_amdgcn_s_setprio(0);
      __syncthreads();
    }
  }
#undef XLOAD

  // ---------- epilogue: weighted atomic scatter-add ----------
  float b2v[2][4];
#pragma unroll
  for (int dh = 0; dh < 2; ++dh)
#pragma unroll
    for (int n = 0; n < 4; ++n)
      b2v[dh][n] = b2[e*DIM + dh*256 + wv*64 + n*16 + r16];
#pragma unroll
  for (int rg = 0; rg < 4; ++rg)
#pragma unroll
    for (int i = 0; i < 4; ++i) {
      int lrow = rg*16 + g4*4 + i;
      if (lrow <= rmax) {
        int gidx = gbase + row0 + lrow;
        int tk = tokl[gidx];
        float wg = pwl[gidx];
#pragma unroll
        for (int dh = 0; dh < 2; ++dh)
#pragma unroll
          for (int n = 0; n < 4; ++n) {
            int d = dh*256 + wv*64 + n*16 + r16;
            atomicAdd(out + (size_t)tk*DIM + d, (acc[rg][dh][n][i] + b2v[dh][n]) * wg);
          }
      }
    }
}

extern "C" void kernel_launch(void* const* d_in, const int* in_sizes, int n_in,
                              void* d_out, int out_size, void* d_ws, size_t ws_size,
                              hipStream_t stream)
{
  const float* x  = (const float*)d_in[0];
  const float* Wr = (const float*)d_in[1];
  const float* W1 = (const float*)d_in[2];
  const float* b1 = (const float*)d_in[3];
  const float* W2 = (const float*)d_in[4];
  const float* b2 = (const float*)d_in[5];
  float* out = (float*)d_out;
  (void)in_sizes; (void)n_in; (void)ws_size;

  char* ws = (char*)d_ws;
  unsigned short* xg  = (unsigned short*)(ws);                    // 128 MB gathered activations
  unsigned short* w1t = (unsigned short*)(ws + 134217728);        // 16 MB W1^T bf16
  unsigned short* w2t = (unsigned short*)(ws + 150994944);        // 16 MB W2^T bf16
  int2*  tinfo = (int2*)(ws + 167772160);                         // 512 KB per-token routing
  int*   tokl  = (int*)(ws + 168296448);                          // 512 KB token list
  float* pwl   = (float*)(ws + 168820736);                        // 512 KB pair weights
  int*   cnt   = (int*)(ws + 169345024);                          // 512 B counts/bases/cursors

  hipMemsetAsync(cnt, 0, NE*16*sizeof(int), stream);
  hipMemsetAsync(d_out, 0, (size_t)out_size*sizeof(float), stream);

  dim3 g1(FF/32, DIM/32, NE);
  k_transpose_cast<<<g1, 256, 0, stream>>>(W1, w1t, DIM, FF);
  dim3 g2(DIM/32, FF/32, NE);
  k_transpose_cast<<<g2, 256, 0, stream>>>(W2, w2t, FF, DIM);

  k_router<<<N_TOK/64, 256, 0, stream>>>(x, Wr, tinfo, cnt);
  k_offsets<<<1, 64, 0, stream>>>(cnt);
  k_fill<<<N_TOK/64, 256, 0, stream>>>(x, tinfo, xg, tokl, pwl, cnt);

  k_ffn<<<NE * (N_TOK/64), 256, 0, stream>>>(xg, w1t, w2t, b1, b2, tokl, pwl, cnt, out);
}

// Round 6
// 1915.671 us; speedup vs baseline: 1.5764x; 1.5764x over previous
//
#include <hip/hip_runtime.h>
#include <cstdint>
#include <cstddef>

#define N_TOK 65536
#define DIM 512
#define FF 2048
#define NE 8

typedef __attribute__((ext_vector_type(8))) short short8;
typedef __attribute__((ext_vector_type(4))) float f32x4;

__device__ __forceinline__ unsigned f2bf(float f) {
  unsigned u = __builtin_bit_cast(unsigned, f);
  u = u + 0x7fffu + ((u >> 16) & 1u);
  return (u >> 16) & 0xffffu;
}

__device__ __forceinline__ void gload_lds16(const void* g, void* l) {
  __builtin_amdgcn_global_load_lds((const __attribute__((address_space(1))) void*)g,
                                   (__attribute__((address_space(3))) void*)l, 16, 0, 0);
}

#define SBAR __builtin_amdgcn_sched_barrier(0)
#define BARN(N) do { SBAR; \
  asm volatile("s_waitcnt vmcnt(" #N ")" ::: "memory"); \
  __builtin_amdgcn_s_barrier(); SBAR; } while (0)

// ---------------- transpose + cast: in (rows x cols) f32 -> out (cols x rows) bf16, per expert
__global__ __launch_bounds__(256) void k_transpose_cast(
    const float* __restrict__ in, unsigned short* __restrict__ outp, int rows, int cols)
{
  __shared__ float tile[32][33];
  const float* ine = in + (size_t)blockIdx.z * rows * cols;
  unsigned short* oute = outp + (size_t)blockIdx.z * rows * cols;
  int tx = threadIdx.x & 31, ty = threadIdx.x >> 5;
  int r0 = blockIdx.y * 32, c0 = blockIdx.x * 32;
#pragma unroll
  for (int i = 0; i < 4; ++i)
    tile[ty + i*8][tx] = ine[(size_t)(r0 + ty + i*8)*cols + c0 + tx];
  __syncthreads();
#pragma unroll
  for (int i = 0; i < 4; ++i) {
    int r = c0 + ty + i*8, c = r0 + tx;
    oute[(size_t)r*rows + c] = (unsigned short)f2bf(tile[tx][ty + i*8]);
  }
}

// ---------------- router pass 1: logits, top-2, weight; per-expert counts only
__global__ __launch_bounds__(256) void k_router(
    const float* __restrict__ x, const float* __restrict__ Wr,
    int2* __restrict__ tinfo, int* __restrict__ cnt)
{
  __shared__ int lcnt[8];
  int tid = threadIdx.x, lane = tid & 63, wv = tid >> 6;
  if (tid < 8) lcnt[tid] = 0;
  float wr[8][8];
#pragma unroll
  for (int j = 0; j < 8; ++j) {
    const float4* p = (const float4*)(Wr + (size_t)(lane*8 + j)*NE);
    float4 a = p[0], b = p[1];
    wr[j][0]=a.x; wr[j][1]=a.y; wr[j][2]=a.z; wr[j][3]=a.w;
    wr[j][4]=b.x; wr[j][5]=b.y; wr[j][6]=b.z; wr[j][7]=b.w;
  }
  __syncthreads();
  int t0 = blockIdx.x*64 + wv*16;
  for (int it = 0; it < 16; ++it) {
    int t = t0 + it;
    const float4* xp = (const float4*)(x + (size_t)t*DIM + lane*8);
    float4 v0 = xp[0], v1 = xp[1];
    float xv[8] = {v0.x,v0.y,v0.z,v0.w,v1.x,v1.y,v1.z,v1.w};
    float lg[8];
#pragma unroll
    for (int e2 = 0; e2 < 8; ++e2) lg[e2] = 0.f;
#pragma unroll
    for (int j = 0; j < 8; ++j)
#pragma unroll
      for (int e2 = 0; e2 < 8; ++e2) lg[e2] += xv[j]*wr[j][e2];
#pragma unroll
    for (int off = 32; off >= 1; off >>= 1)
#pragma unroll
      for (int e2 = 0; e2 < 8; ++e2) lg[e2] += __shfl_xor(lg[e2], off, 64);
    int e0 = 0; float v0m = lg[0];
#pragma unroll
    for (int e2 = 1; e2 < 8; ++e2) if (lg[e2] > v0m) { v0m = lg[e2]; e0 = e2; }
    int e1 = -1; float v1m = -3.0e38f;
#pragma unroll
    for (int e2 = 0; e2 < 8; ++e2) if (e2 != e0 && lg[e2] > v1m) { v1m = lg[e2]; e1 = e2; }
    float w0 = 1.f / (1.f + __expf((v1m - v0m) * 0.4f));   // 1/T = 1/2.5
    if (lane == 0) {
      atomicAdd(&lcnt[e0], 1);
      atomicAdd(&lcnt[e1], 1);
      tinfo[t] = make_int2(e0 | (e1 << 8), __float_as_int(w0));
    }
  }
  __syncthreads();
  if (tid < 8) atomicAdd(&cnt[tid*16], lcnt[tid]);
}

// ---------------- pass 2: exclusive scan of counts -> bases; zero cursors
__global__ void k_offsets(int* cnt) {
  if (threadIdx.x == 0) {
    int base = 0;
    for (int e2 = 0; e2 < 8; ++e2) {
      cnt[e2*16 + 1] = base;
      base += cnt[e2*16];
      cnt[e2*16 + 2] = 0;
    }
  }
}

// ---------------- pass 3: gather x rows (bf16) into contiguous per-expert regions
__global__ __launch_bounds__(256) void k_fill(
    const float* __restrict__ x, const int2* __restrict__ tinfo,
    unsigned short* __restrict__ xg, int* __restrict__ tokl,
    float* __restrict__ pwl, int* __restrict__ cnt)
{
  __shared__ int lc[8], lbase[8], gb[8];
  __shared__ unsigned char ce[128];
  __shared__ int csl[128];
  __shared__ float cw[128];
  int tid = threadIdx.x;
  if (tid < 8) { lc[tid] = 0; gb[tid] = cnt[tid*16 + 1]; }
  __syncthreads();
  if (tid < 64) {
    int t = blockIdx.x*64 + tid;
    int2 inf = tinfo[t];
    int e0 = inf.x & 0xff, e1 = (inf.x >> 8) & 0xff;
    float w0 = __int_as_float(inf.y);
    int i0 = tid*2, i1 = i0 + 1;
    ce[i0] = (unsigned char)e0; cw[i0] = w0;        csl[i0] = atomicAdd(&lc[e0], 1);
    ce[i1] = (unsigned char)e1; cw[i1] = 1.f - w0;  csl[i1] = atomicAdd(&lc[e1], 1);
  }
  __syncthreads();
  if (tid < 8) lbase[tid] = atomicAdd(&cnt[tid*16 + 2], lc[tid]);
  __syncthreads();
  int lane = tid & 63, wv = tid >> 6;
#pragma unroll
  for (int j = 0; j < 32; ++j) {
    int i = wv*32 + j;
    int t = blockIdx.x*64 + (i >> 1);
    int e2 = ce[i];
    int gpos = gb[e2] + lbase[e2] + csl[i];
    const float4* src = (const float4*)(x + (size_t)t*DIM + lane*8);
    float4 v0 = src[0], v1 = src[1];
    uint4 pk;
    pk.x = f2bf(v0.x) | (f2bf(v0.y) << 16);
    pk.y = f2bf(v0.z) | (f2bf(v0.w) << 16);
    pk.z = f2bf(v1.x) | (f2bf(v1.y) << 16);
    pk.w = f2bf(v1.z) | (f2bf(v1.w) << 16);
    *(uint4*)(xg + (size_t)gpos*DIM + lane*8) = pk;
    if (lane == 0) { tokl[gpos] = t; pwl[gpos] = cw[i]; }
  }
}

// ---------------- fused expert FFN v6.
// 128 tok/block, 8 waves, 16x16x32 MFMA. x fully register-resident (fi-invariant, 16 short8/lane).
// Steady-state ledger contains ONLY gload_lds ops -> no compiler waitcnt interference.
// G1: 8 phases, w1 chunk [128f][64k] 16KB, 4-buf, stage pre-barrier (dist-2, ~460cy coverage).
// G2: 4 phases, w2 chunk [512d][32f] 32KB, 2-buf dist-1 (w2_0/w2_1 prefetched in G1 ph6/7).
// b1: 512B LDS slice staged by wave0 into dead w1-buf0 region (self-correcting ledger).
// LDS = 64 (w1) + 64 (w2) + 32 (h) = 160KB exact. All LDS access patterns <=2-way banked.
__global__ __launch_bounds__(512, 2) void k_ffn(
    const unsigned short* __restrict__ xg,
    const unsigned short* __restrict__ w1t,   // (E, F, D) bf16
    const unsigned short* __restrict__ w2t,   // (E, D, F) bf16
    const float* __restrict__ b1, const float* __restrict__ b2,
    const int* __restrict__ tokl, const float* __restrict__ pwl,
    const int* __restrict__ cnt, float* __restrict__ out)
{
  const int e = blockIdx.x & 7;            // expert <-> XCD affinity
  const int tile = blockIdx.x >> 3;
  const int count = cnt[e*16];
  const int row0 = tile * 128;
  if (row0 >= count) return;
  const int gbase = cnt[e*16 + 1];

  __shared__ __align__(16) unsigned short lds[81920];   // 160 KB exact
  unsigned short* w1s = lds;             // 4 bufs x 8192 shorts ([128f][64k] each)
  unsigned short* w2s = lds + 32768;     // 2 bufs x 16384 shorts ([512d][32f] each)
  unsigned short* hsm = lds + 65536;     // [128t][128f], granule ^ (row&15)

  const int tid = threadIdx.x, lane = tid & 63, wv = tid >> 6;
  const int r16 = lane & 15, g4 = lane >> 4;

  const unsigned short* w1e = w1t + (size_t)e*FF*DIM;
  const unsigned short* w2e = w2t + (size_t)e*DIM*FF;
  const unsigned short* xge = xg + (size_t)(gbase + row0)*DIM;

  int rmax = count - row0 - 1; if (rmax > 127) rmax = 127;
  int myrow = wv*16 + r16; if (myrow > rmax) myrow = rmax;
  const unsigned short* xr = xge + (size_t)myrow*DIM;

  auto stage_w1 = [&](int buf, int f0_, int kk_) {
#pragma unroll
    for (int j = 0; j < 2; ++j) {
      int f = j*64 + (tid >> 3);
      gload_lds16(w1e + (size_t)(f0_ + f)*DIM + kk_*64 + (((tid & 7) ^ (f & 7)) << 3),
                  w1s + buf*8192 + j*4096 + tid*8);
    }
  };
  auto stage_w2 = [&](int buf, int foff) {
#pragma unroll
    for (int j = 0; j < 4; ++j) {
      int d = j*128 + (tid >> 2);
      gload_lds16(w2e + (size_t)d*FF + foff + (((tid & 3) ^ ((d >> 1) & 3)) << 3),
                  w2s + buf*16384 + j*4096 + tid*8);
    }
  };

  // ---- prologue: full x row -> 16 short8 regs (issued FIRST in the queue), then w1_0, w1_1 ----
  short8 xf[16];
#pragma unroll
  for (int q = 0; q < 16; ++q)
    xf[q] = *(const short8*)(xr + (q >> 1)*64 + (q & 1)*32 + g4*8);
  SBAR;
  stage_w1(0, 0, 0); SBAR;
  stage_w1(1, 0, 1); SBAR;

  const f32x4 fz = {0.f, 0.f, 0.f, 0.f};
  f32x4 acc[32];
#pragma unroll
  for (int n = 0; n < 32; ++n) acc[n] = fz;

  for (int fi = 0; fi < 16; ++fi) {
    const int f0 = fi << 7;
    f32x4 hacc[8];
#pragma unroll
    for (int n = 0; n < 8; ++n) hacc[n] = fz;

    // ---------- GEMM1: 8 K64-phases; stage pre-barrier; counted vmcnt ----------
#pragma unroll
    for (int kk = 0; kk < 8; ++kk) {
      if (kk < 6)       { stage_w1((kk + 2) & 3, f0, kk + 2); SBAR; }
      else if (kk == 6) { stage_w2(0, f0);
                          if (wv == 0 && lane < 32)
                            gload_lds16(b1 + (size_t)e*FF + f0 + lane*4, w1s);
                          SBAR; }
      else              { stage_w2(1, f0 + 32); SBAR; }
      if (kk < 6)       { BARN(4); }   // wait w1_kk; keep 2 chunks in flight
      else if (kk == 6) { BARN(6); }   // wait w1_6; keep w1_7 + w2_0
      else              { BARN(8); }   // wait w1_7; keep w2_0 + w2_1 (+b1)
      const unsigned short* bc = w1s + (kk & 3)*8192;
      __builtin_amdgcn_s_setprio(1);
#pragma unroll
      for (int k2 = 0; k2 < 2; ++k2) {
#pragma unroll
        for (int n = 0; n < 8; ++n) {
          int f = n*16 + r16;
          short8 b = *(const short8*)(bc + f*64 + ((((k2 << 2) + g4) ^ (f & 7)) << 3));
          hacc[n] = __builtin_amdgcn_mfma_f32_16x16x32_bf16(xf[kk*2 + k2], b, hacc[n], 0, 0, 0);
        }
      }
      __builtin_amdgcn_s_setprio(0);
    }

    // ---------- h-phase: wait w2_0 + b1 slice; build gelu(h); publish ----------
    BARN(4);
    const float* b1p = (const float*)w1s;     // b1 slice overlay (buf0 region, dead)
#pragma unroll
    for (int n = 0; n < 8; ++n) {
      int f = n*16 + r16;
      float bias = b1p[f];
#pragma unroll
      for (int i = 0; i < 4; ++i) {
        int row = wv*16 + g4*4 + i;
        float v = hacc[n][i] + bias;
        float u = 0.7978845608028654f * (v + 0.044715f*v*v*v);
        float gl = v / (1.f + __expf(-2.f*u));   // tanh-approx gelu
        int g = (n*2 + (r16 >> 3)) ^ (row & 15);
        hsm[row*128 + g*8 + (r16 & 7)] = (unsigned short)f2bf(gl);
      }
    }
    SBAR;
    asm volatile("s_waitcnt lgkmcnt(0)" ::: "memory");
    __builtin_amdgcn_s_barrier();
    SBAR;

    // ---------- GEMM2: 4 K32-phases; w2 2-buf dist-1 ----------
#pragma unroll
    for (int s = 0; s < 4; ++s) {
      if (s == 1)      { BARN(0); stage_w2(0, f0 + 64); SBAR; }       // w2_2 -> buf0
      else if (s == 2) { BARN(0); stage_w2(1, f0 + 96); SBAR;         // w2_3 -> buf1
                         if (fi < 15) { stage_w1(0, f0 + 128, 0); SBAR; } }
      else if (s == 3) {
        if (fi < 15) { BARN(2); stage_w1(1, f0 + 128, 1); SBAR; }
        else         { BARN(0); }
      }
      const unsigned short* bc2 = w2s + (s & 1)*16384;
      short8 a = *(const short8*)&hsm[(wv*16 + r16)*128 + ((((s << 2) + g4) ^ r16) << 3)];
      __builtin_amdgcn_s_setprio(1);
#pragma unroll
      for (int n = 0; n < 32; ++n) {
        int d = n*16 + r16;
        short8 b = *(const short8*)(bc2 + d*32 + ((g4 ^ ((d >> 1) & 3)) << 3));
        acc[n] = __builtin_amdgcn_mfma_f32_16x16x32_bf16(a, b, acc[n], 0, 0, 0);
      }
      __builtin_amdgcn_s_setprio(0);
    }
  }

  // ---------- epilogue: weighted atomic scatter-add ----------
  float b2v[32];
#pragma unroll
  for (int n = 0; n < 32; ++n) b2v[n] = b2[e*DIM + n*16 + r16];
#pragma unroll
  for (int i = 0; i < 4; ++i) {
    int lrow = wv*16 + g4*4 + i;
    if (lrow <= rmax) {
      int gidx = gbase + row0 + lrow;
      int tk = tokl[gidx];
      float wg = pwl[gidx];
#pragma unroll
      for (int n = 0; n < 32; ++n) {
        int d = n*16 + r16;
        atomicAdd(out + (size_t)tk*DIM + d, (acc[n][i] + b2v[n]) * wg);
      }
    }
  }
}

extern "C" void kernel_launch(void* const* d_in, const int* in_sizes, int n_in,
                              void* d_out, int out_size, void* d_ws, size_t ws_size,
                              hipStream_t stream)
{
  const float* x  = (const float*)d_in[0];
  const float* Wr = (const float*)d_in[1];
  const float* W1 = (const float*)d_in[2];
  const float* b1 = (const float*)d_in[3];
  const float* W2 = (const float*)d_in[4];
  const float* b2 = (const float*)d_in[5];
  float* out = (float*)d_out;
  (void)in_sizes; (void)n_in; (void)ws_size;

  char* ws = (char*)d_ws;
  unsigned short* xg  = (unsigned short*)(ws);                    // 128 MB gathered activations
  unsigned short* w1t = (unsigned short*)(ws + 134217728);        // 16 MB W1^T bf16
  unsigned short* w2t = (unsigned short*)(ws + 150994944);        // 16 MB W2^T bf16
  int2*  tinfo = (int2*)(ws + 167772160);                         // 512 KB per-token routing
  int*   tokl  = (int*)(ws + 168296448);                          // 512 KB token list
  float* pwl   = (float*)(ws + 168820736);                        // 512 KB pair weights
  int*   cnt   = (int*)(ws + 169345024);                          // 512 B counts/bases/cursors

  hipMemsetAsync(cnt, 0, NE*16*sizeof(int), stream);
  hipMemsetAsync(d_out, 0, (size_t)out_size*sizeof(float), stream);

  dim3 g1(FF/32, DIM/32, NE);
  k_transpose_cast<<<g1, 256, 0, stream>>>(W1, w1t, DIM, FF);
  dim3 g2(DIM/32, FF/32, NE);
  k_transpose_cast<<<g2, 256, 0, stream>>>(W2, w2t, FF, DIM);

  k_router<<<N_TOK/64, 256, 0, stream>>>(x, Wr, tinfo, cnt);
  k_offsets<<<1, 64, 0, stream>>>(cnt);
  k_fill<<<N_TOK/64, 256, 0, stream>>>(x, tinfo, xg, tokl, pwl, cnt);

  k_ffn<<<NE * (N_TOK/128), 512, 0, stream>>>(xg, w1t, w2t, b1, b2, tokl, pwl, cnt, out);
}

// Round 7
// 1402.179 us; speedup vs baseline: 2.1537x; 1.3662x over previous
//
#include <hip/hip_runtime.h>
#include <cstdint>
#include <cstddef>

#define N_TOK 65536
#define DIM 512
#define FF 2048
#define NE 8
#define HCAP 24576           // per-chunk h capacity (rows); nominal expert count ~16384

typedef __attribute__((ext_vector_type(8))) short short8;
typedef __attribute__((ext_vector_type(4))) float f32x4;

__device__ __forceinline__ unsigned f2bf(float f) {
  unsigned u = __builtin_bit_cast(unsigned, f);
  u = u + 0x7fffu + ((u >> 16) & 1u);
  return (u >> 16) & 0xffffu;
}

__device__ __forceinline__ void gload_lds16(const void* g, void* l) {
  __builtin_amdgcn_global_load_lds((const __attribute__((address_space(1))) void*)g,
                                   (__attribute__((address_space(3))) void*)l, 16, 0, 0);
}

// ---------------- transpose + cast: in (rows x cols) f32 -> out (cols x rows) bf16, per expert
__global__ __launch_bounds__(256) void k_transpose_cast(
    const float* __restrict__ in, unsigned short* __restrict__ outp, int rows, int cols)
{
  __shared__ float tile[32][33];
  const float* ine = in + (size_t)blockIdx.z * rows * cols;
  unsigned short* oute = outp + (size_t)blockIdx.z * rows * cols;
  int tx = threadIdx.x & 31, ty = threadIdx.x >> 5;
  int r0 = blockIdx.y * 32, c0 = blockIdx.x * 32;
#pragma unroll
  for (int i = 0; i < 4; ++i)
    tile[ty + i*8][tx] = ine[(size_t)(r0 + ty + i*8)*cols + c0 + tx];
  __syncthreads();
#pragma unroll
  for (int i = 0; i < 4; ++i) {
    int r = c0 + ty + i*8, c = r0 + tx;
    oute[(size_t)r*rows + c] = (unsigned short)f2bf(tile[tx][ty + i*8]);
  }
}

// ---------------- router pass 1: logits, top-2, weight; per-expert counts only
__global__ __launch_bounds__(256) void k_router(
    const float* __restrict__ x, const float* __restrict__ Wr,
    int2* __restrict__ tinfo, int* __restrict__ cnt)
{
  __shared__ int lcnt[8];
  int tid = threadIdx.x, lane = tid & 63, wv = tid >> 6;
  if (tid < 8) lcnt[tid] = 0;
  float wr[8][8];
#pragma unroll
  for (int j = 0; j < 8; ++j) {
    const float4* p = (const float4*)(Wr + (size_t)(lane*8 + j)*NE);
    float4 a = p[0], b = p[1];
    wr[j][0]=a.x; wr[j][1]=a.y; wr[j][2]=a.z; wr[j][3]=a.w;
    wr[j][4]=b.x; wr[j][5]=b.y; wr[j][6]=b.z; wr[j][7]=b.w;
  }
  __syncthreads();
  int t0 = blockIdx.x*64 + wv*16;
  for (int it = 0; it < 16; ++it) {
    int t = t0 + it;
    const float4* xp = (const float4*)(x + (size_t)t*DIM + lane*8);
    float4 v0 = xp[0], v1 = xp[1];
    float xv[8] = {v0.x,v0.y,v0.z,v0.w,v1.x,v1.y,v1.z,v1.w};
    float lg[8];
#pragma unroll
    for (int e2 = 0; e2 < 8; ++e2) lg[e2] = 0.f;
#pragma unroll
    for (int j = 0; j < 8; ++j)
#pragma unroll
      for (int e2 = 0; e2 < 8; ++e2) lg[e2] += xv[j]*wr[j][e2];
#pragma unroll
    for (int off = 32; off >= 1; off >>= 1)
#pragma unroll
      for (int e2 = 0; e2 < 8; ++e2) lg[e2] += __shfl_xor(lg[e2], off, 64);
    int e0 = 0; float v0m = lg[0];
#pragma unroll
    for (int e2 = 1; e2 < 8; ++e2) if (lg[e2] > v0m) { v0m = lg[e2]; e0 = e2; }
    int e1 = -1; float v1m = -3.0e38f;
#pragma unroll
    for (int e2 = 0; e2 < 8; ++e2) if (e2 != e0 && lg[e2] > v1m) { v1m = lg[e2]; e1 = e2; }
    float w0 = 1.f / (1.f + __expf((v1m - v0m) * 0.4f));   // 1/T = 1/2.5
    if (lane == 0) {
      atomicAdd(&lcnt[e0], 1);
      atomicAdd(&lcnt[e1], 1);
      tinfo[t] = make_int2(e0 | (e1 << 8), __float_as_int(w0));
    }
  }
  __syncthreads();
  if (tid < 8) atomicAdd(&cnt[tid*16], lcnt[tid]);
}

// ---------------- pass 2: exclusive scan of counts -> bases; zero cursors
__global__ void k_offsets(int* cnt) {
  if (threadIdx.x == 0) {
    int base = 0;
    for (int e2 = 0; e2 < 8; ++e2) {
      cnt[e2*16 + 1] = base;
      base += cnt[e2*16];
      cnt[e2*16 + 2] = 0;
    }
  }
}

// ---------------- pass 3: gather x rows (bf16) into contiguous per-expert regions
__global__ __launch_bounds__(256) void k_fill(
    const float* __restrict__ x, const int2* __restrict__ tinfo,
    unsigned short* __restrict__ xg, int* __restrict__ tokl,
    float* __restrict__ pwl, int* __restrict__ cnt)
{
  __shared__ int lc[8], lbase[8], gb[8];
  __shared__ unsigned char ce[128];
  __shared__ int csl[128];
  __shared__ float cw[128];
  int tid = threadIdx.x;
  if (tid < 8) { lc[tid] = 0; gb[tid] = cnt[tid*16 + 1]; }
  __syncthreads();
  if (tid < 64) {
    int t = blockIdx.x*64 + tid;
    int2 inf = tinfo[t];
    int e0 = inf.x & 0xff, e1 = (inf.x >> 8) & 0xff;
    float w0 = __int_as_float(inf.y);
    int i0 = tid*2, i1 = i0 + 1;
    ce[i0] = (unsigned char)e0; cw[i0] = w0;        csl[i0] = atomicAdd(&lc[e0], 1);
    ce[i1] = (unsigned char)e1; cw[i1] = 1.f - w0;  csl[i1] = atomicAdd(&lc[e1], 1);
  }
  __syncthreads();
  if (tid < 8) lbase[tid] = atomicAdd(&cnt[tid*16 + 2], lc[tid]);
  __syncthreads();
  int lane = tid & 63, wv = tid >> 6;
#pragma unroll
  for (int j = 0; j < 32; ++j) {
    int i = wv*32 + j;
    int t = blockIdx.x*64 + (i >> 1);
    int e2 = ce[i];
    int gpos = gb[e2] + lbase[e2] + csl[i];
    const float4* src = (const float4*)(x + (size_t)t*DIM + lane*8);
    float4 v0 = src[0], v1 = src[1];
    uint4 pk;
    pk.x = f2bf(v0.x) | (f2bf(v0.y) << 16);
    pk.y = f2bf(v0.z) | (f2bf(v0.w) << 16);
    pk.z = f2bf(v1.x) | (f2bf(v1.y) << 16);
    pk.w = f2bf(v1.z) | (f2bf(v1.w) << 16);
    *(uint4*)(xg + (size_t)gpos*DIM + lane*8) = pk;
    if (lane == 0) { tokl[gpos] = t; pwl[gpos] = cw[i]; }
  }
}

// ================= shared 128x128 GEMM core (m97 structure) =================
// 256 threads, 4 waves in 2x2 grid, each wave 64x64 (4x4 16x16 frags).
// A,B chunks: [128 rows][64 k] bf16, slot-XOR ^(row&7) -> 2-way (free) LDS banking.
// Schedule: stage(next tile, other buf) -> frag reads + MFMA(cur) -> __syncthreads().
// 64KB LDS -> 2 blocks/CU; co-resident block hides the compiler's barrier drain.
__device__ __forceinline__ void stage128(
    const unsigned short* __restrict__ src, size_t stride, int k0,
    unsigned short* __restrict__ buf, int tid)
{
#pragma unroll
  for (int j = 0; j < 4; ++j) {
    int lrow = j*32 + (tid >> 3);
    gload_lds16(src + (size_t)lrow*stride + k0 + (((tid & 7) ^ (lrow & 7)) << 3),
                buf + j*2048 + tid*8);
  }
}

__device__ __forceinline__ void gemm128(
    const unsigned short* __restrict__ Asrc, size_t Astride,
    const unsigned short* __restrict__ Bsrc, size_t Bstride,
    int nk, unsigned short* __restrict__ As, unsigned short* __restrict__ Bs,
    f32x4 acc[4][4], int tid)
{
  const int lane = tid & 63, wv = tid >> 6;
  const int r16 = lane & 15, g4 = lane >> 4;
  const int wm = wv >> 1, wn = wv & 1;

  stage128(Asrc, Astride, 0, As, tid);
  stage128(Bsrc, Bstride, 0, Bs, tid);
  __syncthreads();

  int buf = 0;
  for (int kk = 0; kk < nk; ++kk) {
    if (kk + 1 < nk) {
      stage128(Asrc, Astride, (kk + 1)*64, As + (buf ^ 1)*8192, tid);
      stage128(Bsrc, Bstride, (kk + 1)*64, Bs + (buf ^ 1)*8192, tid);
    }
    const unsigned short* ab = As + buf*8192;
    const unsigned short* bb = Bs + buf*8192;
    short8 af[4][2], bf[4][2];
#pragma unroll
    for (int mf = 0; mf < 4; ++mf) {
      int row = wm*64 + mf*16 + r16;
#pragma unroll
      for (int k2 = 0; k2 < 2; ++k2)
        af[mf][k2] = *(const short8*)(ab + row*64 + ((((k2 << 2) + g4) ^ (row & 7)) << 3));
    }
#pragma unroll
    for (int nf = 0; nf < 4; ++nf) {
      int row = wn*64 + nf*16 + r16;
#pragma unroll
      for (int k2 = 0; k2 < 2; ++k2)
        bf[nf][k2] = *(const short8*)(bb + row*64 + ((((k2 << 2) + g4) ^ (row & 7)) << 3));
    }
    __builtin_amdgcn_s_setprio(1);
#pragma unroll
    for (int k2 = 0; k2 < 2; ++k2)
#pragma unroll
      for (int mf = 0; mf < 4; ++mf)
#pragma unroll
        for (int nf = 0; nf < 4; ++nf)
          acc[mf][nf] = __builtin_amdgcn_mfma_f32_16x16x32_bf16(
              af[mf][k2], bf[nf][k2], acc[mf][nf], 0, 0, 0);
    __builtin_amdgcn_s_setprio(0);
    __syncthreads();
    buf ^= 1;
  }
}

// ---------------- K1: h[rows, FF] = gelu(xg @ W1^T + b1), one expert chunk
__global__ __launch_bounds__(256, 2) void k_gemm1(
    const unsigned short* __restrict__ xg, const unsigned short* __restrict__ w1t,
    const float* __restrict__ b1, const int* __restrict__ cnt,
    unsigned short* __restrict__ h, int e)
{
  const int count0 = cnt[e*16];
  const int count = count0 < HCAP ? count0 : HCAP;
  const int m = blockIdx.x >> 4, n = blockIdx.x & 15;
  const int row0 = m*128;
  if (row0 >= count) return;
  const int gbase = cnt[e*16 + 1];

  __shared__ __align__(16) unsigned short lds[32768];   // 64 KB
  unsigned short* As = lds;
  unsigned short* Bs = lds + 16384;

  const int tid = threadIdx.x, lane = tid & 63, wv = tid >> 6;
  const int r16 = lane & 15, g4 = lane >> 4;
  const int wm = wv >> 1, wn = wv & 1;

  const f32x4 fz = {0.f, 0.f, 0.f, 0.f};
  f32x4 acc[4][4];
#pragma unroll
  for (int a = 0; a < 4; ++a)
#pragma unroll
    for (int b = 0; b < 4; ++b) acc[a][b] = fz;

  gemm128(xg + (size_t)(gbase + row0)*DIM, DIM,
          w1t + (size_t)e*FF*DIM + (size_t)(n*128)*DIM, DIM,
          DIM/64, As, Bs, acc, tid);

  // bias + gelu, bounce through LDS, coalesced h write
  float b1v[4];
#pragma unroll
  for (int nf = 0; nf < 4; ++nf)
    b1v[nf] = b1[(size_t)e*FF + n*128 + wn*64 + nf*16 + r16];

  unsigned short* hs = lds;       // [128][136] overlay (all GEMM reads complete)
#pragma unroll
  for (int mf = 0; mf < 4; ++mf)
#pragma unroll
    for (int nf = 0; nf < 4; ++nf) {
      int col = wn*64 + nf*16 + r16;
#pragma unroll
      for (int i = 0; i < 4; ++i) {
        int row = wm*64 + mf*16 + g4*4 + i;
        float v = acc[mf][nf][i] + b1v[nf];
        float u = 0.7978845608028654f * (v + 0.044715f*v*v*v);
        float gl = v / (1.f + __expf(-2.f*u));     // tanh-approx gelu
        hs[row*136 + col] = (unsigned short)f2bf(gl);
      }
    }
  __syncthreads();
#pragma unroll
  for (int j = 0; j < 8; ++j) {
    int o = j*256 + tid;
    int row = o >> 4, part = o & 15;
    if (row0 + row < count)
      *(uint4*)(h + (size_t)(row0 + row)*FF + n*128 + part*8) =
          *(const uint4*)(hs + row*136 + part*8);
  }
}

// ---------------- K2: out += w * (h @ W2^T + b2), weighted atomic scatter
__global__ __launch_bounds__(256, 2) void k_gemm2(
    const unsigned short* __restrict__ h, const unsigned short* __restrict__ w2t,
    const float* __restrict__ b2, const int* __restrict__ tokl,
    const float* __restrict__ pwl, const int* __restrict__ cnt,
    float* __restrict__ out, int e)
{
  const int count0 = cnt[e*16];
  const int count = count0 < HCAP ? count0 : HCAP;
  const int m = blockIdx.x >> 2, n = blockIdx.x & 3;
  const int row0 = m*128;
  if (row0 >= count) return;
  const int gbase = cnt[e*16 + 1];

  __shared__ __align__(16) unsigned short lds[32768];   // 64 KB
  unsigned short* As = lds;
  unsigned short* Bs = lds + 16384;

  const int tid = threadIdx.x, lane = tid & 63, wv = tid >> 6;
  const int r16 = lane & 15, g4 = lane >> 4;
  const int wm = wv >> 1, wn = wv & 1;

  const f32x4 fz = {0.f, 0.f, 0.f, 0.f};
  f32x4 acc[4][4];
#pragma unroll
  for (int a = 0; a < 4; ++a)
#pragma unroll
    for (int b = 0; b < 4; ++b) acc[a][b] = fz;

  gemm128(h + (size_t)row0*FF, FF,
          w2t + (size_t)e*DIM*FF + (size_t)(n*128)*FF, FF,
          FF/64, As, Bs, acc, tid);

  float b2v[4];
#pragma unroll
  for (int nf = 0; nf < 4; ++nf)
    b2v[nf] = b2[(size_t)e*DIM + n*128 + wn*64 + nf*16 + r16];

#pragma unroll
  for (int mf = 0; mf < 4; ++mf)
#pragma unroll
    for (int i = 0; i < 4; ++i) {
      int lrow = row0 + wm*64 + mf*16 + g4*4 + i;
      if (lrow < count) {
        int tk = tokl[gbase + lrow];
        float wg = pwl[gbase + lrow];
#pragma unroll
        for (int nf = 0; nf < 4; ++nf) {
          int d = n*128 + wn*64 + nf*16 + r16;
          atomicAdd(out + (size_t)tk*DIM + d, (acc[mf][nf][i] + b2v[nf]) * wg);
        }
      }
    }
}

extern "C" void kernel_launch(void* const* d_in, const int* in_sizes, int n_in,
                              void* d_out, int out_size, void* d_ws, size_t ws_size,
                              hipStream_t stream)
{
  const float* x  = (const float*)d_in[0];
  const float* Wr = (const float*)d_in[1];
  const float* W1 = (const float*)d_in[2];
  const float* b1 = (const float*)d_in[3];
  const float* W2 = (const float*)d_in[4];
  const float* b2 = (const float*)d_in[5];
  float* out = (float*)d_out;
  (void)in_sizes; (void)n_in; (void)ws_size;

  char* ws = (char*)d_ws;
  unsigned short* xg  = (unsigned short*)(ws);                    // 134.2 MB gathered activations
  unsigned short* w1t = (unsigned short*)(ws + 134217728);        // 16 MB W1^T bf16
  unsigned short* w2t = (unsigned short*)(ws + 150994944);        // 16 MB W2^T bf16
  int2*  tinfo = (int2*)(ws + 167772160);                         // 512 KB per-token routing
  int*   tokl  = (int*)(ws + 168296448);                          // 512 KB token list
  float* pwl   = (float*)(ws + 168820736);                        // 512 KB pair weights
  int*   cnt   = (int*)(ws + 169345024);                          // 512 B counts/bases
  unsigned short* h = (unsigned short*)(ws + 169345536);          // 100.7 MB h chunk (HCAP rows)

  hipMemsetAsync(cnt, 0, NE*16*sizeof(int), stream);
  hipMemsetAsync(d_out, 0, (size_t)out_size*sizeof(float), stream);

  dim3 g1(FF/32, DIM/32, NE);
  k_transpose_cast<<<g1, 256, 0, stream>>>(W1, w1t, DIM, FF);
  dim3 g2(DIM/32, FF/32, NE);
  k_transpose_cast<<<g2, 256, 0, stream>>>(W2, w2t, FF, DIM);

  k_router<<<N_TOK/64, 256, 0, stream>>>(x, Wr, tinfo, cnt);
  k_offsets<<<1, 64, 0, stream>>>(cnt);
  k_fill<<<N_TOK/64, 256, 0, stream>>>(x, tinfo, xg, tokl, pwl, cnt);

  for (int e = 0; e < NE; ++e) {
    k_gemm1<<<(HCAP/128)*16, 256, 0, stream>>>(xg, w1t, b1, cnt, h, e);
    k_gemm2<<<(HCAP/128)*4, 256, 0, stream>>>(h, w2t, b2, tokl, pwl, cnt, out, e);
  }
}